// Round 1
// baseline (234.288 us; speedup 1.0000x reference)
//
#include <hip/hip_runtime.h>

typedef __bf16 bf16_t;
typedef bf16_t bf16x8 __attribute__((ext_vector_type(8)));
typedef float f32x4 __attribute__((ext_vector_type(4)));
typedef unsigned short u16x4 __attribute__((ext_vector_type(4)));
typedef unsigned int u32x4v __attribute__((ext_vector_type(4)));

#define DEV static __device__ __forceinline__

// ---------- helpers ----------

DEV unsigned short f2bf(float f) {
  unsigned int u = __builtin_bit_cast(unsigned int, f);
  u = (u + 0x7fffu + ((u >> 16) & 1u)) >> 16;  // RNE
  return (unsigned short)u;
}

DEV void async_ld16(const unsigned short* gsrc, unsigned short* lbase, int lane) {
#if __has_builtin(__builtin_amdgcn_global_load_lds)
  __builtin_amdgcn_global_load_lds(
      (const __attribute__((address_space(1))) unsigned int*)(const void*)gsrc,
      (__attribute__((address_space(3))) unsigned int*)(void*)lbase, 16, 0, 0);
#else
  *reinterpret_cast<u32x4v*>(reinterpret_cast<char*>(lbase) + lane * 16) =
      *reinterpret_cast<const u32x4v*>(gsrc);
#endif
}

// ---------- fp32 -> bf16 convert ----------

__global__ __launch_bounds__(256) void cvt_f32_to_bf16(const float* __restrict__ src,
                                                       unsigned short* __restrict__ dst,
                                                       int n8) {
  int i = blockIdx.x * blockDim.x + threadIdx.x;
  if (i >= n8) return;
  const float4* s = reinterpret_cast<const float4*>(src) + (size_t)i * 2;
  float4 a = s[0], c = s[1];
  u16x4 lo = {f2bf(a.x), f2bf(a.y), f2bf(a.z), f2bf(a.w)};
  u16x4 hi = {f2bf(c.x), f2bf(c.y), f2bf(c.z), f2bf(c.w)};
  u16x4* d = reinterpret_cast<u16x4*>(dst) + (size_t)i * 2;
  d[0] = lo;
  d[1] = hi;
}

// ---------- shared 128x128-tile GEMM core: out[m,n] = sum_k X[m,k]*W[n,k] ----------
// LDS tiles are [128 rows][64 k] bf16, linear (global_load_lds-compatible) with
// 16B-chunk XOR swizzle applied on the GLOBAL source address; reads XOR the same
// pattern -> conflict-free ds_read_b128.

DEV void stage_tile_128x64(const unsigned short* __restrict__ G, int row0, int k0,
                           unsigned short* lbuf, int lane, int wv) {
#pragma unroll
  for (int r = 0; r < 4; ++r) {
    const int rowA = (r * 4 + wv) * 8 + (lane >> 3);
    const int chunk = (lane & 7) ^ (rowA & 7);
    const unsigned short* gsrc = G + (size_t)(row0 + rowA) * 1024 + k0 + chunk * 8;
    unsigned short* lbase = lbuf + (r * 4 + wv) * 512;  // 1KB per wave-round
    async_ld16(gsrc, lbase, lane);
  }
}

DEV void gemm_core(const unsigned short* __restrict__ X, const unsigned short* __restrict__ W,
                   unsigned short* lA, unsigned short* lB, int bm0, int bn0, int lane, int wv,
                   int wm, int wn, f32x4 acc[4][4]) {
  for (int kt = 0; kt < 16; ++kt) {
    __syncthreads();
    stage_tile_128x64(X, bm0, kt * 64, lA, lane, wv);
    stage_tile_128x64(W, bn0, kt * 64, lB, lane, wv);
    __syncthreads();
#pragma unroll
    for (int kk = 0; kk < 2; ++kk) {
      bf16x8 af[4], bfr[4];
#pragma unroll
      for (int f = 0; f < 4; ++f) {
        const int rowA = wm * 64 + f * 16 + (lane & 15);
        const int cA = (kk * 4 + (lane >> 4)) ^ (rowA & 7);
        af[f] = *reinterpret_cast<const bf16x8*>(lA + rowA * 64 + cA * 8);
        const int rowB = wn * 64 + f * 16 + (lane & 15);
        const int cB = (kk * 4 + (lane >> 4)) ^ (rowB & 7);
        bfr[f] = *reinterpret_cast<const bf16x8*>(lB + rowB * 64 + cB * 8);
      }
#pragma unroll
      for (int i = 0; i < 4; ++i)
#pragma unroll
        for (int j = 0; j < 4; ++j)
          acc[i][j] = __builtin_amdgcn_mfma_f32_16x16x32_bf16(af[i], bfr[j], acc[i][j], 0, 0, 0);
    }
  }
}

// ---------- QKV projection (z = 0/1/2 -> Q/K/V), output bf16 [B,H,S,dk] ----------

__global__ __launch_bounds__(256) void gemm_qkv_kernel(
    const unsigned short* __restrict__ Xq, const unsigned short* __restrict__ Xk,
    const unsigned short* __restrict__ Xv, const unsigned short* __restrict__ Wq,
    const unsigned short* __restrict__ Wk, const unsigned short* __restrict__ Wv,
    const float* __restrict__ bq, const float* __restrict__ bk, const float* __restrict__ bv,
    unsigned short* __restrict__ Qp, unsigned short* __restrict__ Kp,
    unsigned short* __restrict__ Vp) {
  __shared__ unsigned short lA[128 * 64];
  __shared__ unsigned short lB[128 * 64];
  const unsigned short* X;
  const unsigned short* W;
  const float* bias;
  unsigned short* dst;
  if (blockIdx.z == 0) { X = Xq; W = Wq; bias = bq; dst = Qp; }
  else if (blockIdx.z == 1) { X = Xk; W = Wk; bias = bk; dst = Kp; }
  else { X = Xv; W = Wv; bias = bv; dst = Vp; }
  const int lane = threadIdx.x & 63, wv = threadIdx.x >> 6;
  const int wm = wv >> 1, wn = wv & 1;
  const int bm0 = blockIdx.x * 128, bn0 = blockIdx.y * 128;
  f32x4 acc[4][4] = {};
  gemm_core(X, W, lA, lB, bm0, bn0, lane, wv, wm, wn, acc);
#pragma unroll
  for (int i = 0; i < 4; ++i) {
    const int mbase = bm0 + wm * 64 + i * 16 + ((lane >> 4) << 2);
#pragma unroll
    for (int j = 0; j < 4; ++j) {
      const int n = bn0 + wn * 64 + j * 16 + (lane & 15);
      const float bia = bias[n];
      const int h = n >> 6, d = n & 63;
#pragma unroll
      for (int r = 0; r < 4; ++r) {
        const int m = mbase + r;
        const int b = m >> 11, s = m & 2047;
        dst[((size_t)(b * 16 + h) * 2048 + s) * 64 + d] = f2bf(acc[i][j][r] + bia);
      }
    }
  }
}

// ---------- output projection: fp32 out = Ob @ Wo^T + bo ----------

__global__ __launch_bounds__(256) void gemm_out_kernel(const unsigned short* __restrict__ X,
                                                       const unsigned short* __restrict__ W,
                                                       const float* __restrict__ bias,
                                                       float* __restrict__ out) {
  __shared__ unsigned short lA[128 * 64];
  __shared__ unsigned short lB[128 * 64];
  const int lane = threadIdx.x & 63, wv = threadIdx.x >> 6;
  const int wm = wv >> 1, wn = wv & 1;
  const int bm0 = blockIdx.x * 128, bn0 = blockIdx.y * 128;
  f32x4 acc[4][4] = {};
  gemm_core(X, W, lA, lB, bm0, bn0, lane, wv, wm, wn, acc);
#pragma unroll
  for (int i = 0; i < 4; ++i) {
    const int mbase = bm0 + wm * 64 + i * 16 + ((lane >> 4) << 2);
#pragma unroll
    for (int j = 0; j < 4; ++j) {
      const int n = bn0 + wn * 64 + j * 16 + (lane & 15);
      const float bia = bias[n];
#pragma unroll
      for (int r = 0; r < 4; ++r) out[(size_t)(mbase + r) * 1024 + n] = acc[i][j][r] + bia;
    }
  }
}

// ---------- flash attention with ALiBi (swapped QK^T; online softmax) ----------
// Block: 4 waves x 16 q-rows (QBLK=64); KV tile = 64. grid = (S/64, B*H).

__global__ __launch_bounds__(256) void attn_kernel(const unsigned short* __restrict__ Qp,
                                                   const unsigned short* __restrict__ Kp,
                                                   const unsigned short* __restrict__ Vp,
                                                   unsigned short* __restrict__ Ob) {
  __shared__ unsigned short Vt[64 * 72];     // V^T tile [d][kv], +8 pad
  __shared__ unsigned short Pl[4][16 * 72];  // per-wave P [q][kv], +8 pad
  const int lane = threadIdx.x & 63, wv = threadIdx.x >> 6;
  const int bh = blockIdx.y;  // b*16 + h
  const int h = bh & 15, b = bh >> 4;
  const int qt = blockIdx.x;
  const int q_glob = qt * 64 + wv * 16 + (lane & 15);
  const float slope = exp2f((float)(h - 8));
  const size_t headoff = (size_t)bh * 2048 * 64;
  const unsigned short* Qh = Qp + headoff;
  const unsigned short* Kh = Kp + headoff;
  const unsigned short* Vh = Vp + headoff;

  bf16x8 qf[2];
#pragma unroll
  for (int kk = 0; kk < 2; ++kk)
    qf[kk] = *reinterpret_cast<const bf16x8*>(Qh + (size_t)q_glob * 64 + kk * 32 +
                                              (lane >> 4) * 8);

  f32x4 acc_o[4] = {};
  float m_run = -3.0e38f, l_run = 0.0f;

  const int sd = threadIdx.x & 63;   // staging: d index
  const int stg = threadIdx.x >> 6;  // staging: kv group of 16

  for (int t = 0; t < 32; ++t) {
    const int kv0 = t * 64;
    __syncthreads();  // protect Vt from previous iteration's readers
    // stage V^T: Vt[d][kv] = V[kv0+kv][d]
    {
      unsigned short vals[16];
#pragma unroll
      for (int i = 0; i < 16; ++i) vals[i] = Vh[(size_t)(kv0 + stg * 16 + i) * 64 + sd];
#pragma unroll
      for (int g = 0; g < 4; ++g) {
        u16x4 pk = {vals[4 * g], vals[4 * g + 1], vals[4 * g + 2], vals[4 * g + 3]};
        *reinterpret_cast<u16x4*>(reinterpret_cast<char*>(Vt) + sd * 144 + stg * 32 + g * 8) = pk;
      }
    }
    // swapped QK^T: S^T[kv][q] — K direct from global as A, Q regs as B
    f32x4 sacc[4] = {};
#pragma unroll
    for (int fk = 0; fk < 4; ++fk) {
#pragma unroll
      for (int kk = 0; kk < 2; ++kk) {
        bf16x8 kf = *reinterpret_cast<const bf16x8*>(
            Kh + (size_t)(kv0 + fk * 16 + (lane & 15)) * 64 + kk * 32 + (lane >> 4) * 8);
        sacc[fk] = __builtin_amdgcn_mfma_f32_16x16x32_bf16(kf, qf[kk], sacc[fk], 0, 0, 0);
      }
    }
    __syncthreads();  // Vt ready
    // scale + ALiBi + online softmax (q is lane-local: col = lane&15)
    float sv[16];
    float m_tile = -3.0e38f;
#pragma unroll
    for (int fk = 0; fk < 4; ++fk)
#pragma unroll
      for (int r = 0; r < 4; ++r) {
        const int kvg = kv0 + fk * 16 + ((lane >> 4) << 2) + r;
        const float x = sacc[fk][r] * 0.125f + slope * (float)(q_glob - kvg);
        sv[fk * 4 + r] = x;
        m_tile = fmaxf(m_tile, x);
      }
    m_tile = fmaxf(m_tile, __shfl_xor(m_tile, 16));
    m_tile = fmaxf(m_tile, __shfl_xor(m_tile, 32));
    const float m_new = fmaxf(m_run, m_tile);
    const float alpha = __expf(m_run - m_new);
    float psum = 0.0f;
    unsigned short pb[16];
#pragma unroll
    for (int i = 0; i < 16; ++i) {
      const float p = __expf(sv[i] - m_new);
      psum += p;
      pb[i] = f2bf(p);
    }
    psum += __shfl_xor(psum, 16);
    psum += __shfl_xor(psum, 32);
    l_run = l_run * alpha + psum;
    m_run = m_new;
#pragma unroll
    for (int fd = 0; fd < 4; ++fd) acc_o[fd] *= alpha;
    // P -> per-wave LDS [q][kv] (packed b64 writes), then read as PV B-operand
    char* Pw = reinterpret_cast<char*>(Pl[wv]);
#pragma unroll
    for (int fk = 0; fk < 4; ++fk) {
      u16x4 pk = {pb[4 * fk], pb[4 * fk + 1], pb[4 * fk + 2], pb[4 * fk + 3]};
      *reinterpret_cast<u16x4*>(Pw + (lane & 15) * 144 + fk * 32 + (lane >> 4) * 8) = pk;
    }
    bf16x8 pfr[2];
#pragma unroll
    for (int kk = 0; kk < 2; ++kk)
      pfr[kk] =
          *reinterpret_cast<const bf16x8*>(Pw + (lane & 15) * 144 + kk * 64 + (lane >> 4) * 16);
    // PV: O^T[d][q] += V^T[d][kv] * P^T[kv][q]
#pragma unroll
    for (int fd = 0; fd < 4; ++fd)
#pragma unroll
      for (int kk = 0; kk < 2; ++kk) {
        bf16x8 vf = *reinterpret_cast<const bf16x8*>(
            reinterpret_cast<char*>(Vt) + (fd * 16 + (lane & 15)) * 144 + kk * 64 +
            (lane >> 4) * 16);
        acc_o[fd] = __builtin_amdgcn_mfma_f32_16x16x32_bf16(vf, pfr[kk], acc_o[fd], 0, 0, 0);
      }
  }
  // epilogue: normalize, write Ob[b, q, h*64+d] as bf16
  const float inv_l = 1.0f / l_run;
#pragma unroll
  for (int fd = 0; fd < 4; ++fd) {
    const int d0 = fd * 16 + ((lane >> 4) << 2);
    u16x4 pk;
#pragma unroll
    for (int r = 0; r < 4; ++r) pk[r] = f2bf(acc_o[fd][r] * inv_l);
    *reinterpret_cast<u16x4*>(Ob + ((size_t)(b * 2048 + q_glob)) * 1024 + h * 64 + d0) = pk;
  }
}

// ---------- launcher ----------

extern "C" void kernel_launch(void* const* d_in, const int* in_sizes, int n_in, void* d_out,
                              int out_size, void* d_ws, size_t ws_size, hipStream_t stream) {
  const float* q = (const float*)d_in[0];
  const float* k = (const float*)d_in[1];
  const float* v = (const float*)d_in[2];
  const float* Wq = (const float*)d_in[3];
  const float* bq = (const float*)d_in[4];
  const float* Wk = (const float*)d_in[5];
  const float* bk = (const float*)d_in[6];
  const float* Wv = (const float*)d_in[7];
  const float* bv = (const float*)d_in[8];
  const float* Wo = (const float*)d_in[9];
  const float* bo = (const float*)d_in[10];

  char* ws = (char*)d_ws;
  const size_t MB = 1024 * 1024;
  unsigned short* qb = (unsigned short*)(ws + 0 * MB);    // 8MB
  unsigned short* kb = (unsigned short*)(ws + 8 * MB);    // 8MB
  unsigned short* vb = (unsigned short*)(ws + 16 * MB);   // 8MB
  unsigned short* Wqb = (unsigned short*)(ws + 24 * MB);  // 2MB
  unsigned short* Wkb = (unsigned short*)(ws + 26 * MB);
  unsigned short* Wvb = (unsigned short*)(ws + 28 * MB);
  unsigned short* Wob = (unsigned short*)(ws + 30 * MB);
  unsigned short* Qp = (unsigned short*)(ws + 32 * MB);  // 8MB, [B,H,S,dk]
  unsigned short* Kp = (unsigned short*)(ws + 40 * MB);
  unsigned short* Vp = (unsigned short*)(ws + 48 * MB);
  unsigned short* Obf = (unsigned short*)(ws + 0 * MB);  // reuse qb region (qb dead after QKV GEMM)

  cvt_f32_to_bf16<<<2048, 256, 0, stream>>>(q, qb, 524288);
  cvt_f32_to_bf16<<<2048, 256, 0, stream>>>(k, kb, 524288);
  cvt_f32_to_bf16<<<2048, 256, 0, stream>>>(v, vb, 524288);
  cvt_f32_to_bf16<<<512, 256, 0, stream>>>(Wq, Wqb, 131072);
  cvt_f32_to_bf16<<<512, 256, 0, stream>>>(Wk, Wkb, 131072);
  cvt_f32_to_bf16<<<512, 256, 0, stream>>>(Wv, Wvb, 131072);
  cvt_f32_to_bf16<<<512, 256, 0, stream>>>(Wo, Wob, 131072);

  gemm_qkv_kernel<<<dim3(32, 8, 3), 256, 0, stream>>>(qb, kb, vb, Wqb, Wkb, Wvb, bq, bk, bv, Qp,
                                                      Kp, Vp);
  attn_kernel<<<dim3(32, 32), 256, 0, stream>>>(Qp, Kp, Vp, Obf);
  gemm_out_kernel<<<dim3(32, 8), 256, 0, stream>>>(Obf, Wob, bo, (float*)d_out);
}

// Round 2
// 158.721 us; speedup vs baseline: 1.4761x; 1.4761x over previous
//
#include <hip/hip_runtime.h>

typedef __bf16 bf16_t;
typedef bf16_t bf16x8 __attribute__((ext_vector_type(8)));
typedef float f32x4 __attribute__((ext_vector_type(4)));
typedef float f32x16 __attribute__((ext_vector_type(16)));
typedef unsigned short u16x4 __attribute__((ext_vector_type(4)));
typedef unsigned int u32x4v __attribute__((ext_vector_type(4)));
typedef unsigned int u32;

#define DEV static __device__ __forceinline__

// ---------- helpers ----------

DEV unsigned short f2bf(float f) {
  unsigned int u = __builtin_bit_cast(unsigned int, f);
  u = (u + 0x7fffu + ((u >> 16) & 1u)) >> 16;  // RNE
  return (unsigned short)u;
}

DEV float fexp2(float x) {  // 2^x via v_exp_f32
  float r;
  asm("v_exp_f32 %0, %1" : "=v"(r) : "v"(x));
  return r;
}

DEV u32 cvtpk(float lo, float hi_) {  // packed bf16 pair (RNE)
  u32 r;
  asm("v_cvt_pk_bf16_f32 %0, %1, %2" : "=v"(r) : "v"(lo), "v"(hi_));
  return r;
}

DEV void plswap(u32& a, u32& b) {  // swap a.hi32lanes <-> b.lo32lanes
  asm("v_permlane32_swap_b32 %0, %1" : "+v"(a), "+v"(b));
}

DEV void async_ld16(const unsigned short* gsrc, unsigned short* lbase, int lane) {
#if __has_builtin(__builtin_amdgcn_global_load_lds)
  __builtin_amdgcn_global_load_lds(
      (const __attribute__((address_space(1))) unsigned int*)(const void*)gsrc,
      (__attribute__((address_space(3))) unsigned int*)(void*)lbase, 16, 0, 0);
#else
  *reinterpret_cast<u32x4v*>(reinterpret_cast<char*>(lbase) + lane * 16) =
      *reinterpret_cast<const u32x4v*>(gsrc);
#endif
}

// ---------- fp32 -> bf16 converts (merged launches) ----------

DEV void cvt_body(const float* __restrict__ src, unsigned short* __restrict__ dst, int i) {
  const float4* s = reinterpret_cast<const float4*>(src) + (size_t)i * 2;
  float4 a = s[0], c = s[1];
  u16x4 lo = {f2bf(a.x), f2bf(a.y), f2bf(a.z), f2bf(a.w)};
  u16x4 hi = {f2bf(c.x), f2bf(c.y), f2bf(c.z), f2bf(c.w)};
  u16x4* d = reinterpret_cast<u16x4*>(dst) + (size_t)i * 2;
  d[0] = lo;
  d[1] = hi;
}

__global__ __launch_bounds__(256) void cvt_qkv(const float* __restrict__ q,
                                               const float* __restrict__ k,
                                               const float* __restrict__ v,
                                               unsigned short* dq, unsigned short* dk,
                                               unsigned short* dv) {
  const int i = blockIdx.x * 256 + threadIdx.x;
  const float* src = blockIdx.z == 0 ? q : blockIdx.z == 1 ? k : v;
  unsigned short* dst = blockIdx.z == 0 ? dq : blockIdx.z == 1 ? dk : dv;
  cvt_body(src, dst, i);
}

__global__ __launch_bounds__(256) void cvt_w(const float* __restrict__ a,
                                             const float* __restrict__ b,
                                             const float* __restrict__ c,
                                             const float* __restrict__ d, unsigned short* da,
                                             unsigned short* db_, unsigned short* dc,
                                             unsigned short* dd) {
  const int i = blockIdx.x * 256 + threadIdx.x;
  const float* src = blockIdx.z == 0 ? a : blockIdx.z == 1 ? b : blockIdx.z == 2 ? c : d;
  unsigned short* dst = blockIdx.z == 0 ? da : blockIdx.z == 1 ? db_ : blockIdx.z == 2 ? dc : dd;
  cvt_body(src, dst, i);
}

// ---------- shared 128x128-tile GEMM core: out[m,n] = sum_k X[m,k]*W[n,k] ----------

DEV void stage_tile_128x64(const unsigned short* __restrict__ G, int row0, int k0,
                           unsigned short* lbuf, int lane, int wv) {
#pragma unroll
  for (int r = 0; r < 4; ++r) {
    const int rowA = (r * 4 + wv) * 8 + (lane >> 3);
    const int chunk = (lane & 7) ^ (rowA & 7);
    const unsigned short* gsrc = G + (size_t)(row0 + rowA) * 1024 + k0 + chunk * 8;
    unsigned short* lbase = lbuf + (r * 4 + wv) * 512;
    async_ld16(gsrc, lbase, lane);
  }
}

DEV void gemm_core(const unsigned short* __restrict__ X, const unsigned short* __restrict__ W,
                   unsigned short* lA, unsigned short* lB, int bm0, int bn0, int lane, int wv,
                   int wm, int wn, f32x4 acc[4][4]) {
  for (int kt = 0; kt < 16; ++kt) {
    __syncthreads();
    stage_tile_128x64(X, bm0, kt * 64, lA, lane, wv);
    stage_tile_128x64(W, bn0, kt * 64, lB, lane, wv);
    __syncthreads();
#pragma unroll
    for (int kk = 0; kk < 2; ++kk) {
      bf16x8 af[4], bfr[4];
#pragma unroll
      for (int f = 0; f < 4; ++f) {
        const int rowA = wm * 64 + f * 16 + (lane & 15);
        const int cA = (kk * 4 + (lane >> 4)) ^ (rowA & 7);
        af[f] = *reinterpret_cast<const bf16x8*>(lA + rowA * 64 + cA * 8);
        const int rowB = wn * 64 + f * 16 + (lane & 15);
        const int cB = (kk * 4 + (lane >> 4)) ^ (rowB & 7);
        bfr[f] = *reinterpret_cast<const bf16x8*>(lB + rowB * 64 + cB * 8);
      }
#pragma unroll
      for (int i = 0; i < 4; ++i)
#pragma unroll
        for (int j = 0; j < 4; ++j)
          acc[i][j] = __builtin_amdgcn_mfma_f32_16x16x32_bf16(af[i], bfr[j], acc[i][j], 0, 0, 0);
    }
  }
}

// ---------- QKV projection; Q,K -> [B,H,S,dk]; V -> TRANSPOSED [B,H,dk,S] ----------

__global__ __launch_bounds__(256) void gemm_qkv_kernel(
    const unsigned short* __restrict__ Xq, const unsigned short* __restrict__ Xk,
    const unsigned short* __restrict__ Xv, const unsigned short* __restrict__ Wq,
    const unsigned short* __restrict__ Wk, const unsigned short* __restrict__ Wv,
    const float* __restrict__ bq, const float* __restrict__ bk, const float* __restrict__ bv,
    unsigned short* __restrict__ Qp, unsigned short* __restrict__ Kp,
    unsigned short* __restrict__ Vp) {
  __shared__ unsigned short lA[128 * 64];
  __shared__ unsigned short lB[128 * 64];
  const unsigned short* X;
  const unsigned short* W;
  const float* bias;
  unsigned short* dst;
  if (blockIdx.z == 0) { X = Xq; W = Wq; bias = bq; dst = Qp; }
  else if (blockIdx.z == 1) { X = Xk; W = Wk; bias = bk; dst = Kp; }
  else { X = Xv; W = Wv; bias = bv; dst = Vp; }
  const bool zV = (blockIdx.z == 2);
  const int lane = threadIdx.x & 63, wv = threadIdx.x >> 6;
  const int wm = wv >> 1, wn = wv & 1;
  const int bm0 = blockIdx.x * 128, bn0 = blockIdx.y * 128;
  f32x4 acc[4][4] = {};
  gemm_core(X, W, lA, lB, bm0, bn0, lane, wv, wm, wn, acc);
#pragma unroll
  for (int i = 0; i < 4; ++i) {
    const int mbase = bm0 + wm * 64 + i * 16 + ((lane >> 4) << 2);
#pragma unroll
    for (int j = 0; j < 4; ++j) {
      const int n = bn0 + wn * 64 + j * 16 + (lane & 15);
      const float bia = bias[n];
      const int h = n >> 6, d = n & 63;
#pragma unroll
      for (int r = 0; r < 4; ++r) {
        const int m = mbase + r;
        const int b = m >> 11, s = m & 2047;
        const unsigned short val = f2bf(acc[i][j][r] + bia);
        if (zV)
          dst[((size_t)(b * 16 + h) * 64 + d) * 2048 + s] = val;
        else
          dst[((size_t)(b * 16 + h) * 2048 + s) * 64 + d] = val;
      }
    }
  }
}

// ---------- output projection: fp32 out = Ob @ Wo^T + bo ----------

__global__ __launch_bounds__(256) void gemm_out_kernel(const unsigned short* __restrict__ X,
                                                       const unsigned short* __restrict__ W,
                                                       const float* __restrict__ bias,
                                                       float* __restrict__ out) {
  __shared__ unsigned short lA[128 * 64];
  __shared__ unsigned short lB[128 * 64];
  const int lane = threadIdx.x & 63, wv = threadIdx.x >> 6;
  const int wm = wv >> 1, wn = wv & 1;
  const int bm0 = blockIdx.x * 128, bn0 = blockIdx.y * 128;
  f32x4 acc[4][4] = {};
  gemm_core(X, W, lA, lB, bm0, bn0, lane, wv, wm, wn, acc);
#pragma unroll
  for (int i = 0; i < 4; ++i) {
    const int mbase = bm0 + wm * 64 + i * 16 + ((lane >> 4) << 2);
#pragma unroll
    for (int j = 0; j < 4; ++j) {
      const int n = bn0 + wn * 64 + j * 16 + (lane & 15);
      const float bia = bias[n];
#pragma unroll
      for (int r = 0; r < 4; ++r) out[(size_t)(mbase + r) * 1024 + n] = acc[i][j][r] + bia;
    }
  }
}

// ---------- flash attention, 32x32 swapped-QK^T, in-register softmax ----------
// Block: 4 waves x 32 q-rows = 128 q. KV tile 64, K/V^T double-buffered in LDS.
// grid = (S/128, B*H).

DEV void stage_tile64(const unsigned short* __restrict__ Gbase, size_t stride, int colbase,
                      unsigned short* lbuf, int lane, int wv) {
#pragma unroll
  for (int i = 0; i < 2; ++i) {
    const int r = i * 32 + wv * 8 + (lane >> 3);
    const int chunk = (lane & 7) ^ (r & 7);
    async_ld16(Gbase + (size_t)r * stride + colbase + chunk * 8, lbuf + (i * 32 + wv * 8) * 64,
               lane);
  }
}

__global__ __launch_bounds__(256) void attn_kernel(const unsigned short* __restrict__ Qp,
                                                   const unsigned short* __restrict__ Kp,
                                                   const unsigned short* __restrict__ VTp,
                                                   unsigned short* __restrict__ Ob) {
  __shared__ unsigned short Kb[2][64 * 64];
  __shared__ unsigned short Vb[2][64 * 64];
  const int lane = threadIdx.x & 63, wv = threadIdx.x >> 6;
  const int lq = lane & 31, hi = lane >> 5;
  const int bh = blockIdx.y, h = bh & 15, b = bh >> 4;
  const int q_glob = blockIdx.x * 128 + wv * 32 + lq;
  const float L2E = 1.4426950408889634f;
  const float slope2 = ldexpf(L2E, h - 8);  // slope * log2(e)
  const float SC2 = 0.125f * L2E;           // 1/sqrt(dk) * log2(e)
  const size_t headoff = (size_t)bh * 2048 * 64;
  const unsigned short* Qh = Qp + headoff;
  const unsigned short* Kh = Kp + headoff;
  const unsigned short* VTh = VTp + headoff;

  float alC[16];
#pragma unroll
  for (int r = 0; r < 16; ++r) alC[r] = slope2 * (float)((r & 3) + 8 * (r >> 2));

  bf16x8 qf[4];
#pragma unroll
  for (int tt = 0; tt < 4; ++tt)
    qf[tt] = *reinterpret_cast<const bf16x8*>(Qh + (size_t)q_glob * 64 + tt * 16 + hi * 8);

  f32x16 acc0 = {}, acc1 = {};
  float m_run = -3.0e38f, l_run = 0.0f;

  stage_tile64(Kh, 64, 0, Kb[0], lane, wv);
  stage_tile64(VTh, 2048, 0, Vb[0], lane, wv);
  __syncthreads();

  for (int t = 0; t < 32; ++t) {
    const int kv0 = t * 64;
    const unsigned short* Kc = Kb[t & 1];
    const unsigned short* Vc = Vb[t & 1];
    if (t < 31) {  // prefetch next tile into the other buffer
      stage_tile64(Kh + (size_t)(kv0 + 64) * 64, 64, 0, Kb[(t + 1) & 1], lane, wv);
      stage_tile64(VTh, 2048, kv0 + 64, Vb[(t + 1) & 1], lane, wv);
    }
    // QK^T (swapped): S^T[kv][q]; s0 = kv 0..31, s1 = kv 32..63
    f32x16 s0 = {}, s1 = {};
#pragma unroll
    for (int tt = 0; tt < 4; ++tt) {
      {
        const int row = lq;
        const int ch = (tt * 2 + hi) ^ (row & 7);
        bf16x8 kf = *reinterpret_cast<const bf16x8*>(Kc + row * 64 + ch * 8);
        s0 = __builtin_amdgcn_mfma_f32_32x32x16_bf16(kf, qf[tt], s0, 0, 0, 0);
      }
      {
        const int row = 32 + lq;
        const int ch = (tt * 2 + hi) ^ (row & 7);
        bf16x8 kf = *reinterpret_cast<const bf16x8*>(Kc + row * 64 + ch * 8);
        s1 = __builtin_amdgcn_mfma_f32_32x32x16_bf16(kf, qf[tt], s1, 0, 0, 0);
      }
    }
    // softmax in exp2 domain; lane holds 32 kv values of q-row (lane&31);
    // partner lane (^32) holds the other 32 (kv offset +4 interleave)
    const float a0 = slope2 * (float)(q_glob - kv0 - 4 * hi);
    const float a1 = a0 - slope2 * 32.0f;
    float xmax = -3.0e38f;
#pragma unroll
    for (int r = 0; r < 16; ++r) {
      const float x0 = __builtin_fmaf(s0[r], SC2, a0) - alC[r];
      const float x1 = __builtin_fmaf(s1[r], SC2, a1) - alC[r];
      s0[r] = x0;
      s1[r] = x1;
      xmax = fmaxf(xmax, fmaxf(x0, x1));
    }
    xmax = fmaxf(xmax, __shfl_xor(xmax, 32));
    const float m_new = fmaxf(m_run, xmax);
    const float alpha = fexp2(m_run - m_new);
    float psum = 0.0f;
#pragma unroll
    for (int r = 0; r < 16; ++r) {
      const float p0 = fexp2(s0[r] - m_new);
      const float p1 = fexp2(s1[r] - m_new);
      s0[r] = p0;
      s1[r] = p1;
      psum += p0 + p1;
    }
    psum += __shfl_xor(psum, 32);
    l_run = l_run * alpha + psum;
    m_run = m_new;
    acc0 *= alpha;
    acc1 *= alpha;
    // P -> bf16 B-frags in-register (cvt_pk + permlane32_swap)
    bf16x8 pf[4];
#pragma unroll
    for (int half = 0; half < 2; ++half) {
      u32 w0 = cvtpk(s0[half * 8 + 0], s0[half * 8 + 1]);
      u32 w2 = cvtpk(s0[half * 8 + 4], s0[half * 8 + 5]);
      plswap(w0, w2);
      u32 w1 = cvtpk(s0[half * 8 + 2], s0[half * 8 + 3]);
      u32 w3 = cvtpk(s0[half * 8 + 6], s0[half * 8 + 7]);
      plswap(w1, w3);
      u32x4v ww = {w0, w1, w2, w3};
      pf[half] = __builtin_bit_cast(bf16x8, ww);
    }
#pragma unroll
    for (int half = 0; half < 2; ++half) {
      u32 w0 = cvtpk(s1[half * 8 + 0], s1[half * 8 + 1]);
      u32 w2 = cvtpk(s1[half * 8 + 4], s1[half * 8 + 5]);
      plswap(w0, w2);
      u32 w1 = cvtpk(s1[half * 8 + 2], s1[half * 8 + 3]);
      u32 w3 = cvtpk(s1[half * 8 + 6], s1[half * 8 + 7]);
      plswap(w1, w3);
      u32x4v ww = {w0, w1, w2, w3};
      pf[2 + half] = __builtin_bit_cast(bf16x8, ww);
    }
    // PV: O^T[d][q] += V^T[d][kv] * P[q][kv]
#pragma unroll
    for (int tt = 0; tt < 4; ++tt) {
      {
        const int row = lq;
        const int ch = (tt * 2 + hi) ^ (row & 7);
        bf16x8 vf = *reinterpret_cast<const bf16x8*>(Vc + row * 64 + ch * 8);
        acc0 = __builtin_amdgcn_mfma_f32_32x32x16_bf16(vf, pf[tt], acc0, 0, 0, 0);
      }
      {
        const int row = 32 + lq;
        const int ch = (tt * 2 + hi) ^ (row & 7);
        bf16x8 vf = *reinterpret_cast<const bf16x8*>(Vc + row * 64 + ch * 8);
        acc1 = __builtin_amdgcn_mfma_f32_32x32x16_bf16(vf, pf[tt], acc1, 0, 0, 0);
      }
    }
    __syncthreads();
  }
  // epilogue: normalize, write Ob[b, q, h*64+d] (bf16), d = db*32 + g*8 + 4*hi + i
  const float inv_l = 1.0f / l_run;
  unsigned short* Orow = Ob + (size_t)(b * 2048 + q_glob) * 1024 + h * 64;
#pragma unroll
  for (int g = 0; g < 4; ++g) {
    u16x4 pk0, pk1;
#pragma unroll
    for (int i2 = 0; i2 < 4; ++i2) {
      pk0[i2] = f2bf(acc0[g * 4 + i2] * inv_l);
      pk1[i2] = f2bf(acc1[g * 4 + i2] * inv_l);
    }
    *reinterpret_cast<u16x4*>(Orow + g * 8 + 4 * hi) = pk0;
    *reinterpret_cast<u16x4*>(Orow + 32 + g * 8 + 4 * hi) = pk1;
  }
}

// ---------- launcher ----------

extern "C" void kernel_launch(void* const* d_in, const int* in_sizes, int n_in, void* d_out,
                              int out_size, void* d_ws, size_t ws_size, hipStream_t stream) {
  const float* q = (const float*)d_in[0];
  const float* k = (const float*)d_in[1];
  const float* v = (const float*)d_in[2];
  const float* Wq = (const float*)d_in[3];
  const float* bq = (const float*)d_in[4];
  const float* Wk = (const float*)d_in[5];
  const float* bk = (const float*)d_in[6];
  const float* Wv = (const float*)d_in[7];
  const float* bv = (const float*)d_in[8];
  const float* Wo = (const float*)d_in[9];
  const float* bo = (const float*)d_in[10];

  char* ws = (char*)d_ws;
  const size_t MB = 1024 * 1024;
  unsigned short* qb = (unsigned short*)(ws + 0 * MB);    // 8MB
  unsigned short* kb = (unsigned short*)(ws + 8 * MB);    // 8MB
  unsigned short* vb = (unsigned short*)(ws + 16 * MB);   // 8MB
  unsigned short* Wqb = (unsigned short*)(ws + 24 * MB);  // 2MB each
  unsigned short* Wkb = (unsigned short*)(ws + 26 * MB);
  unsigned short* Wvb = (unsigned short*)(ws + 28 * MB);
  unsigned short* Wob = (unsigned short*)(ws + 30 * MB);
  unsigned short* Qp = (unsigned short*)(ws + 32 * MB);  // [B,H,S,dk]
  unsigned short* Kp = (unsigned short*)(ws + 40 * MB);  // [B,H,S,dk]
  unsigned short* VTp = (unsigned short*)(ws + 48 * MB); // [B,H,dk,S] (transposed)
  unsigned short* Obf = (unsigned short*)(ws + 0 * MB);  // reuse qb region

  cvt_qkv<<<dim3(2048, 1, 3), 256, 0, stream>>>(q, k, v, qb, kb, vb);
  cvt_w<<<dim3(512, 1, 4), 256, 0, stream>>>(Wq, Wk, Wv, Wo, Wqb, Wkb, Wvb, Wob);

  gemm_qkv_kernel<<<dim3(32, 8, 3), 256, 0, stream>>>(qb, kb, vb, Wqb, Wkb, Wvb, bq, bk, bv, Qp,
                                                      Kp, VTp);
  attn_kernel<<<dim3(16, 32), 256, 0, stream>>>(Qp, Kp, VTp, Obf);
  gemm_out_kernel<<<dim3(32, 8), 256, 0, stream>>>(Obf, Wob, bo, (float*)d_out);
}